// Round 6
// baseline (710.574 us; speedup 1.0000x reference)
//
#include <hip/hip_runtime.h>
#include <stdint.h>

// SelfAttention: B=4, S=4096, D=768, causal, fp32 in/out, bf16 MFMA compute.
// cvt -> qkv GEMM -> scores GEMM (exp epilogue, packed causal P tiles)
//     -> PV GEMM (/l epilogue).
// Round 6: k-loops load fragments DIRECTLY global->VGPR (no LDS staging, no
// per-iteration barriers) so the compiler pipelines loads against MFMAs with
// fine-grained vmcnt. Epilogues are round-4's proven coalesced forms.
// ws layout (bf16 elements):
//   qb  12582912 @ 0           [b][s][e]
//   kb  12582912 @ 12582912    [b][s][e]
//   vt  12582912 @ 25165824    [b][e][s] (V transposed)
//   xb  12582912 @ 37748736    (dead after qkv_proj)
//   wb   1769472 @ 50331648    (dead after qkv_proj)
//   pb  34603008 @ 37748736    ALIAS over xb/wb: packed causal P tiles [q][k],
//                              tile (b, mt, nt<=mt) at slot b*528+mt(mt+1)/2+nt
//   ls  16384 fp32 @ elem 72351744
#define SEQ 4096
#define DIM 768

typedef __attribute__((ext_vector_type(8))) short short8;
typedef __attribute__((ext_vector_type(8))) unsigned short ushort8;
typedef __attribute__((ext_vector_type(4))) unsigned short ushort4v;
typedef __attribute__((ext_vector_type(4))) float fx4;
typedef unsigned short ushort;

#define MFMA16(a, b, c) __builtin_amdgcn_mfma_f32_16x16x32_bf16((a), (b), (c), 0, 0, 0)

__device__ __forceinline__ ushort f2bf(float f) {
  union { float f; unsigned int u; } v; v.f = f;
  return (ushort)((v.u + 0x7fffu + ((v.u >> 16) & 1u)) >> 16);
}
__device__ __forceinline__ float bf2f(ushort u) {
  union { unsigned int u; float f; } v; v.u = ((unsigned int)u) << 16;
  return v.f;
}

// ---------- kernel 0: fused fp32->bf16 casts + ls zero ----------
__global__ void cvt_all(const float* __restrict__ x, const float* __restrict__ wq,
                        const float* __restrict__ wk, const float* __restrict__ wv,
                        ushort* __restrict__ xb, ushort* __restrict__ wb,
                        float* __restrict__ ls) {
  const int bid = blockIdx.x;
  if (bid < 6144) {
    if (bid < 64) ls[bid * 256 + threadIdx.x] = 0.0f;
    const int i = (bid * 256 + threadIdx.x) * 8;
    fx4 a = *(const fx4*)(x + i);
    fx4 b = *(const fx4*)(x + i + 4);
    ushort8 o;
#pragma unroll
    for (int c = 0; c < 4; c++) { o[c] = f2bf(a[c]); o[c + 4] = f2bf(b[c]); }
    *(ushort8*)(xb + i) = o;
  } else {
    const int i = ((bid - 6144) * 256 + threadIdx.x) * 8;
    const int which = i / (DIM * DIM);
    const int off = i - which * (DIM * DIM);
    const float* src = (which == 0) ? wq : (which == 1) ? wk : wv;
    fx4 a = *(const fx4*)(src + off);
    fx4 b = *(const fx4*)(src + off + 4);
    ushort8 o;
#pragma unroll
    for (int c = 0; c < 4; c++) { o[c] = f2bf(a[c]); o[c + 4] = f2bf(b[c]); }
    *(ushort8*)(wb + i) = o;
  }
}

// ---------- kernel 1: QKV projection (128x128 tile, direct-global k-loop) ----
// A=x (rows=s), B=W (rows=e) -> C[s][e]. Q/K: LDS-transpose epilogue, 16B
// coalesced [s][e] stores. V: direct [e][s] 8B stores.
__global__ __launch_bounds__(256, 3)
void qkv_proj(const ushort* __restrict__ xb, const ushort* __restrict__ wb,
              ushort* __restrict__ qb, ushort* __restrict__ kb,
              ushort* __restrict__ vt) {
  __shared__ ushort ys[17408];  // 128 x 136 epilogue transpose (Q/K only)

  const int mb = blockIdx.x, nb = blockIdx.y;
  const int which = nb / 6;
  const int e0 = (nb % 6) * 128;
  const int m0 = mb * 128;
  const int tid = threadIdx.x;
  const int w = tid >> 6, lane = tid & 63, ln = lane & 15, quad = lane >> 4;
  const int wm = (w >> 1) * 64, wn = (w & 1) * 64;

  const ushort* W = wb + (size_t)which * (DIM * DIM);

  const ushort* pa[4];
  const ushort* pbp[4];
#pragma unroll
  for (int i = 0; i < 4; i++)
    pa[i] = xb + (size_t)(m0 + wm + i * 16 + ln) * DIM + quad * 8;
#pragma unroll
  for (int j = 0; j < 4; j++)
    pbp[j] = W + (size_t)(e0 + wn + j * 16 + ln) * DIM + quad * 8;

  fx4 acc[4][4];
#pragma unroll
  for (int i = 0; i < 4; i++)
#pragma unroll
    for (int j = 0; j < 4; j++) acc[i][j] = (fx4)0.0f;

#pragma unroll
  for (int kk = 0; kk < DIM; kk += 64) {
    short8 a0[4], a1[4], b0[4], b1[4];
#pragma unroll
    for (int i = 0; i < 4; i++) {
      a0[i] = *(const short8*)(pa[i] + kk);
      a1[i] = *(const short8*)(pa[i] + kk + 32);
    }
#pragma unroll
    for (int j = 0; j < 4; j++) {
      b0[j] = *(const short8*)(pbp[j] + kk);
      b1[j] = *(const short8*)(pbp[j] + kk + 32);
    }
#pragma unroll
    for (int i = 0; i < 4; i++)
#pragma unroll
      for (int j = 0; j < 4; j++)
        acc[i][j] = MFMA16(a0[i], b0[j], acc[i][j]);
#pragma unroll
    for (int i = 0; i < 4; i++)
#pragma unroll
      for (int j = 0; j < 4; j++)
        acc[i][j] = MFMA16(a1[i], b1[j], acc[i][j]);
  }

  if (which == 2) {
    // C[row=s][col=e]: lane holds 4 consecutive s at fixed e -> vt[e][s] 8B
#pragma unroll
    for (int i = 0; i < 4; i++)
#pragma unroll
      for (int j = 0; j < 4; j++) {
        const int s = m0 + wm + i * 16 + quad * 4;
        const int e = e0 + wn + j * 16 + ln;
        const int bb = s >> 12, si = s & 4095;
        ushort4v p;
#pragma unroll
        for (int r = 0; r < 4; r++) p[r] = f2bf(acc[i][j][r]);
        *(ushort4v*)(vt + ((size_t)bb * DIM + e) * SEQ + si) = p;
      }
  } else {
#pragma unroll
    for (int i = 0; i < 4; i++)
#pragma unroll
      for (int j = 0; j < 4; j++)
#pragma unroll
        for (int r = 0; r < 4; r++)
          ys[(wm + i * 16 + quad * 4 + r) * 136 + wn + j * 16 + ln] =
              f2bf(acc[i][j][r]);
    __syncthreads();
    ushort* dst = (which == 0) ? qb : kb;
#pragma unroll
    for (int p = 0; p < 8; p++) {
      const int tt = p * 256 + tid;
      const int row = tt >> 4, col = (tt & 15) * 8;
      ushort8 v = *(const ushort8*)&ys[row * 136 + col];
      *(ushort8*)(dst + (size_t)(m0 + row) * DIM + e0 + col) = v;
    }
  }
}

// ---------- kernel 2: scores GEMM + exp epilogue (direct-global k-loop) -----
// A=Q (rows=q), B=K (rows=k) -> C[q][k]; P[q][k] packed via LDS, 16B stores.
__global__ __launch_bounds__(256, 3)
void attn_scores(const ushort* __restrict__ qb, const ushort* __restrict__ kb,
                 ushort* __restrict__ pb, float* __restrict__ ls) {
  __shared__ ushort ys[17408];  // 128 x 136 epilogue pack

  const int pr = blockIdx.x;
  const int b = blockIdx.y;
  int mt = (int)(0.5f * (sqrtf(8.0f * pr + 1.0f) - 1.0f));
  while ((mt + 1) * (mt + 2) / 2 <= pr) ++mt;
  while (mt * (mt + 1) / 2 > pr) --mt;
  const int nt = pr - mt * (mt + 1) / 2;
  const int m0 = mt * 128, n0 = nt * 128;

  const int tid = threadIdx.x;
  const int w = tid >> 6, lane = tid & 63, ln = lane & 15, quad = lane >> 4;
  const int wm = (w >> 1) * 64, wn = (w & 1) * 64;
  const size_t qkbase = (size_t)b * SEQ * DIM;
  const float scale = 0.03608439182435161f;  // 1/sqrt(768)

  const ushort* pa[4];
  const ushort* pbp[4];
#pragma unroll
  for (int i = 0; i < 4; i++)
    pa[i] = qb + qkbase + (size_t)(m0 + wm + i * 16 + ln) * DIM + quad * 8;
#pragma unroll
  for (int j = 0; j < 4; j++)
    pbp[j] = kb + qkbase + (size_t)(n0 + wn + j * 16 + ln) * DIM + quad * 8;

  fx4 acc[4][4];
#pragma unroll
  for (int i = 0; i < 4; i++)
#pragma unroll
    for (int j = 0; j < 4; j++) acc[i][j] = (fx4)0.0f;

#pragma unroll
  for (int kk = 0; kk < DIM; kk += 64) {
    short8 a0[4], a1[4], b0[4], b1[4];
#pragma unroll
    for (int i = 0; i < 4; i++) {
      a0[i] = *(const short8*)(pa[i] + kk);
      a1[i] = *(const short8*)(pa[i] + kk + 32);
    }
#pragma unroll
    for (int j = 0; j < 4; j++) {
      b0[j] = *(const short8*)(pbp[j] + kk);
      b1[j] = *(const short8*)(pbp[j] + kk + 32);
    }
#pragma unroll
    for (int i = 0; i < 4; i++)
#pragma unroll
      for (int j = 0; j < 4; j++)
        acc[i][j] = MFMA16(a0[i], b0[j], acc[i][j]);
#pragma unroll
    for (int i = 0; i < 4; i++)
#pragma unroll
      for (int j = 0; j < 4; j++)
        acc[i][j] = MFMA16(a1[i], b1[j], acc[i][j]);
  }

  // epilogue: exp + causal mask + row sums + pack via LDS
  float rowp[4][4];
#pragma unroll
  for (int i = 0; i < 4; i++) {
#pragma unroll
    for (int r = 0; r < 4; r++) rowp[i][r] = 0.0f;
#pragma unroll
    for (int j = 0; j < 4; j++) {
      const int col = n0 + wn + j * 16 + ln;
#pragma unroll
      for (int r = 0; r < 4; r++) {
        const int row = m0 + wm + i * 16 + quad * 4 + r;
        float p = 0.0f;
        if (col <= row) p = __expf(acc[i][j][r] * scale);
        const ushort pk = f2bf(p);
        ys[(wm + i * 16 + quad * 4 + r) * 136 + wn + j * 16 + ln] = pk;
        rowp[i][r] += bf2f(pk);
      }
    }
  }
#pragma unroll
  for (int i = 0; i < 4; i++)
#pragma unroll
    for (int r = 0; r < 4; r++) {
      float s = rowp[i][r];
      s += __shfl_xor(s, 1);
      s += __shfl_xor(s, 2);
      s += __shfl_xor(s, 4);
      s += __shfl_xor(s, 8);
      if (ln == 0)
        atomicAdd(ls + b * SEQ + m0 + wm + i * 16 + quad * 4 + r, s);
    }
  __syncthreads();
  ushort* pt = pb + ((size_t)(b * 528 + pr) << 14);
#pragma unroll
  for (int p = 0; p < 8; p++) {
    const int tt = p * 256 + tid;
    const int row = tt >> 4, col = (tt & 15) * 8;
    ushort8 v = *(const ushort8*)&ys[row * 136 + col];
    *(ushort8*)(pt + row * 128 + col) = v;
  }
}

// ---------- kernel 3: O = P @ V (direct-global k-loop, serpentine) ----------
// A=P (rows=q, packed tiles), B=vt (rows=e) -> C[q][e], /l epilogue.
__global__ __launch_bounds__(256, 3)
void attn_pv(const ushort* __restrict__ pb, const ushort* __restrict__ vt,
             const float* __restrict__ ls, float* __restrict__ out) {
  // serpentine rank -> (mt desc, et, b): balances per-CU work
  int idx = blockIdx.x;
  int chunk = idx >> 8, pos = idx & 255;
  if (chunk & 1) pos = 255 - pos;
  const int r_ = (chunk << 8) + pos;
  const int mt = 31 - r_ / 24;
  const int rem = r_ % 24;
  const int b = rem & 3;
  const int et = rem >> 2;
  const int m0 = mt * 128, e0 = et * 128;

  const int tid = threadIdx.x;
  const int w = tid >> 6, lane = tid & 63, ln = lane & 15, quad = lane >> 4;
  const int wm = (w >> 1) * 64, wn = (w & 1) * 64;
  const size_t vtbase = (size_t)b * DIM * SEQ;
  const ushort* ptiles = pb + ((size_t)(b * 528 + mt * (mt + 1) / 2) << 14);

  const ushort* pa[4];
  const ushort* pbp[4];
#pragma unroll
  for (int i = 0; i < 4; i++)
    pa[i] = ptiles + (wm + i * 16 + ln) * 128 + quad * 8;
#pragma unroll
  for (int j = 0; j < 4; j++)
    pbp[j] = vt + vtbase + (size_t)(e0 + wn + j * 16 + ln) * SEQ + quad * 8;

  fx4 acc[4][4];
#pragma unroll
  for (int i = 0; i < 4; i++)
#pragma unroll
    for (int j = 0; j < 4; j++) acc[i][j] = (fx4)0.0f;

  for (int ntile = 0; ntile <= mt; ntile++) {
    const size_t aoff = (size_t)ntile * 16384;
    const int kglob = ntile * 128;
#pragma unroll
    for (int half = 0; half < 2; half++) {
      const int kin = half * 64;
      short8 a0[4], a1[4], b0[4], b1[4];
#pragma unroll
      for (int i = 0; i < 4; i++) {
        a0[i] = *(const short8*)(pa[i] + aoff + kin);
        a1[i] = *(const short8*)(pa[i] + aoff + kin + 32);
      }
#pragma unroll
      for (int j = 0; j < 4; j++) {
        b0[j] = *(const short8*)(pbp[j] + kglob + kin);
        b1[j] = *(const short8*)(pbp[j] + kglob + kin + 32);
      }
#pragma unroll
      for (int i = 0; i < 4; i++)
#pragma unroll
        for (int j = 0; j < 4; j++)
          acc[i][j] = MFMA16(a0[i], b0[j], acc[i][j]);
#pragma unroll
      for (int i = 0; i < 4; i++)
#pragma unroll
        for (int j = 0; j < 4; j++)
          acc[i][j] = MFMA16(a1[i], b1[j], acc[i][j]);
    }
  }

  // epilogue: C[row=q][col=e] -> out[q][e], /l
#pragma unroll
  for (int i = 0; i < 4; i++)
#pragma unroll
    for (int r = 0; r < 4; r++) {
      const int row = m0 + wm + i * 16 + quad * 4 + r;
      const float linv = 1.0f / ls[b * SEQ + row];
      float* orow = out + ((size_t)(b * SEQ + row)) * DIM + e0 + wn + ln;
#pragma unroll
      for (int j = 0; j < 4; j++) orow[j * 16] = acc[i][j][r] * linv;
    }
}

extern "C" void kernel_launch(void* const* d_in, const int* in_sizes, int n_in,
                              void* d_out, int out_size, void* d_ws, size_t ws_size,
                              hipStream_t stream) {
  const float* x = (const float*)d_in[0];
  const float* wq = (const float*)d_in[1];
  const float* wk = (const float*)d_in[2];
  const float* wv = (const float*)d_in[3];
  float* out = (float*)d_out;

  ushort* qb = (ushort*)d_ws;
  ushort* kb = qb + 12582912;
  ushort* vt = kb + 12582912;
  ushort* xb = vt + 12582912;
  ushort* wb = xb + 12582912;
  ushort* pb = xb;  // alias: xb/wb dead after qkv_proj
  float* ls = (float*)((ushort*)d_ws + 72351744);

  cvt_all<<<7008, 256, 0, stream>>>(x, wq, wk, wv, xb, wb, ls);
  qkv_proj<<<dim3(128, 18), 256, 0, stream>>>(xb, wb, qb, kb, vt);
  attn_scores<<<dim3(528, 4), 256, 0, stream>>>(qb, kb, pb, ls);
  attn_pv<<<768, 256, 0, stream>>>(pb, vt, ls, out);
}